// Round 1
// baseline (2397.355 us; speedup 1.0000x reference)
//
#include <hip/hip_runtime.h>

// ---------------------------------------------------------------------------
// RGCN link predictor, fp32.
//   rgcn_conv(x) = x@root + b + sum_r segsum_dst( H_r[src] ) / max(cnt_r[dst],1)
//   with H_r = x @ W[r] computed per-NODE (16x fewer FLOPs than per-edge).
//   Per-relation mean folded to edge level: edge e adds H[t_e][src_e]/cnt[t_e][dst_e].
// ---------------------------------------------------------------------------

__global__ __launch_bounds__(256) void count_kernel(
    const int* __restrict__ ei, const int* __restrict__ et,
    float* __restrict__ cnt, int E, int N) {
  int e = blockIdx.x * 256 + threadIdx.x;
  if (e >= E) return;
  int d = ei[E + e];
  int t = et[e];
  atomicAdd(&cnt[(size_t)t * N + d], 1.0f);
}

__global__ __launch_bounds__(256) void invert_kernel(float* __restrict__ cnt, int n) {
  int i = blockIdx.x * 256 + threadIdx.x;
  if (i < n) cnt[i] = 1.0f / fmaxf(cnt[i], 1.0f);
}

__global__ __launch_bounds__(256) void relu_kernel(float* __restrict__ p, long long n) {
  long long i = (long long)blockIdx.x * 256 + threadIdx.x;
  if (i < n) p[i] = fmaxf(p[i], 0.0f);
}

// Tiled GEMM: C[n x TN] = A[n x K] @ B[K x TN] (+bias). blockIdx.y selects
// which weight matrix (B += y*K*TN) and which output slab (C += y*n*TN).
template <int K, int TN>
__global__ __launch_bounds__(256) void gemm_kernel(
    const float* __restrict__ A, const float* __restrict__ B,
    const float* __restrict__ bias, float* __restrict__ C, int n) {
  __shared__ float As[64][K + 1];
  __shared__ float Bs[K][TN];
  const int tid = threadIdx.x;
  const int rowBase = blockIdx.x * 64;
  B += (size_t)blockIdx.y * K * TN;
  C += (size_t)blockIdx.y * (size_t)n * TN;

  // load B tile (whole weight matrix): K*TN floats
  for (int i = tid * 4; i < K * TN; i += 1024) {
    *(float4*)&Bs[0][i] = *(const float4*)&B[i];
  }
  // load A tile: 64 x K
  for (int i = tid * 4; i < 64 * K; i += 1024) {
    int r = i / K, c = i % K;
    float4 v = make_float4(0.f, 0.f, 0.f, 0.f);
    if (rowBase + r < n) v = *(const float4*)&A[(size_t)(rowBase + r) * K + c];
    As[r][c] = v.x; As[r][c + 1] = v.y; As[r][c + 2] = v.z; As[r][c + 3] = v.w;
  }
  __syncthreads();

  constexpr int WN = TN / 16;           // cols per thread (4 or 2)
  const int row0 = (tid / 16) * 4;      // 16 row-groups x 4 rows = 64
  const int col0 = (tid % 16) * WN;

  float acc[4][WN];
#pragma unroll
  for (int i = 0; i < 4; i++)
#pragma unroll
    for (int j = 0; j < WN; j++) acc[i][j] = 0.0f;

#pragma unroll 8
  for (int k = 0; k < K; k++) {
    float a0 = As[row0][k], a1 = As[row0 + 1][k];
    float a2 = As[row0 + 2][k], a3 = As[row0 + 3][k];
#pragma unroll
    for (int j = 0; j < WN; j++) {
      float b = Bs[k][col0 + j];
      acc[0][j] += a0 * b;
      acc[1][j] += a1 * b;
      acc[2][j] += a2 * b;
      acc[3][j] += a3 * b;
    }
  }

#pragma unroll
  for (int i = 0; i < 4; i++) {
    int r = rowBase + row0 + i;
    if (r < n) {
#pragma unroll
      for (int j = 0; j < WN; j++) {
        float v = acc[i][j] + (bias ? bias[col0 + j] : 0.0f);
        C[(size_t)r * TN + col0 + j] = v;
      }
    }
  }
}

// Scatter: C/4 lanes per edge, each lane handles a float4 of channels.
template <int C>
__global__ __launch_bounds__(256) void scatter_kernel(
    const float* __restrict__ H, const int* __restrict__ ei,
    const int* __restrict__ et, const float* __restrict__ inv,
    float* __restrict__ out, int E, int N) {
  constexpr int L = C / 4;  // lanes per edge (16 or 8)
  long long g = (long long)blockIdx.x * 256 + threadIdx.x;
  int e = (int)(g / L);
  int q = (int)(g % L);
  if (e >= E) return;
  int s = ei[e];
  int d = ei[E + e];
  int t = et[e];
  float sc = inv[(size_t)t * N + d];
  float4 v = *(const float4*)&H[((size_t)t * N + s) * C + q * 4];
  float* o = &out[(size_t)d * C + q * 4];
  atomicAdd(o + 0, v.x * sc);
  atomicAdd(o + 1, v.y * sc);
  atomicAdd(o + 2, v.z * sc);
  atomicAdd(o + 3, v.w * sc);
}

// Decoder: one thread per pred edge. Wd1 broadcast from LDS.
__global__ __launch_bounds__(256) void decoder_kernel(
    const float* __restrict__ z, const int* __restrict__ pe,
    const float* __restrict__ Wd1, const float* __restrict__ bd1,
    const float* __restrict__ Wd2, const float* __restrict__ bd2,
    float* __restrict__ out, int P) {
  __shared__ float W[64 * 64];
  __shared__ float w2[64], b1s[64];
  int tid = threadIdx.x;
  for (int i = tid * 4; i < 4096; i += 1024) *(float4*)&W[i] = *(const float4*)&Wd1[i];
  if (tid < 64) {
    w2[tid] = Wd2[tid];
    b1s[tid] = bd1[tid];
  }
  __syncthreads();
  int p = blockIdx.x * 256 + tid;
  if (p >= P) return;
  int s = pe[p];
  int d = pe[P + p];
  float zs[32], zd[32];
  const float4* ps4 = (const float4*)&z[(size_t)s * 32];
  const float4* pd4 = (const float4*)&z[(size_t)d * 32];
#pragma unroll
  for (int i = 0; i < 8; i++) {
    float4 a = ps4[i];
    zs[4 * i] = a.x; zs[4 * i + 1] = a.y; zs[4 * i + 2] = a.z; zs[4 * i + 3] = a.w;
    float4 b = pd4[i];
    zd[4 * i] = b.x; zd[4 * i + 1] = b.y; zd[4 * i + 2] = b.z; zd[4 * i + 3] = b.w;
  }
  float acc = bd2[0];
#pragma unroll 4
  for (int j = 0; j < 64; j++) {
    float h = b1s[j];
#pragma unroll
    for (int i = 0; i < 32; i++) h += zs[i] * W[i * 64 + j];
#pragma unroll
    for (int i = 0; i < 32; i++) h += zd[i] * W[(32 + i) * 64 + j];
    h = fmaxf(h, 0.0f);
    acc += h * w2[j];
  }
  out[p] = acc;
}

extern "C" void kernel_launch(void* const* d_in, const int* in_sizes, int n_in,
                              void* d_out, int out_size, void* d_ws, size_t ws_size,
                              hipStream_t stream) {
  const float* x     = (const float*)d_in[0];
  const int*   ei    = (const int*)d_in[1];
  const int*   et    = (const int*)d_in[2];
  const int*   pe    = (const int*)d_in[3];
  const float* W1    = (const float*)d_in[4];
  const float* root1 = (const float*)d_in[5];
  const float* b1    = (const float*)d_in[6];
  const float* W2    = (const float*)d_in[7];
  const float* root2 = (const float*)d_in[8];
  const float* b2    = (const float*)d_in[9];
  const float* Wd1   = (const float*)d_in[10];
  const float* bd1   = (const float*)d_in[11];
  const float* Wd2   = (const float*)d_in[12];
  const float* bd2   = (const float*)d_in[13];
  float* out = (float*)d_out;

  const int N = in_sizes[0] / 128;  // 100000
  const int E = in_sizes[2];        // 1600000
  const int P = in_sizes[3] / 2;    // 200000

  // Workspace layout (floats):
  //   cnt/inv : 3N      z1 : 64N      z2 : 32N      H : 3*N*64 (reused layer2)
  float* ws  = (float*)d_ws;
  float* cnt = ws;
  float* z1  = cnt + (size_t)3 * N;
  float* z2  = z1 + (size_t)64 * N;
  float* H   = z2 + (size_t)32 * N;

  // --- counts (shared by both layers: same edge set) ---
  hipMemsetAsync(cnt, 0, (size_t)3 * N * sizeof(float), stream);
  count_kernel<<<(E + 255) / 256, 256, 0, stream>>>(ei, et, cnt, E, N);
  invert_kernel<<<(3 * N + 255) / 256, 256, 0, stream>>>(cnt, 3 * N);

  const int gb = (N + 63) / 64;

  // --- layer 1: K=128 -> 64 ---
  gemm_kernel<128, 64><<<dim3(gb, 3), 256, 0, stream>>>(x, W1, nullptr, H, N);
  gemm_kernel<128, 64><<<dim3(gb, 1), 256, 0, stream>>>(x, root1, b1, z1, N);
  {
    long long threads = (long long)E * 16;
    scatter_kernel<64><<<(threads + 255) / 256, 256, 0, stream>>>(H, ei, et, cnt, z1, E, N);
  }
  relu_kernel<<<((long long)64 * N + 255) / 256, 256, 0, stream>>>(z1, (long long)64 * N);

  // --- layer 2: K=64 -> 32 ---
  gemm_kernel<64, 32><<<dim3(gb, 3), 256, 0, stream>>>(z1, W2, nullptr, H, N);
  gemm_kernel<64, 32><<<dim3(gb, 1), 256, 0, stream>>>(z1, root2, b2, z2, N);
  {
    long long threads = (long long)E * 8;
    scatter_kernel<32><<<(threads + 255) / 256, 256, 0, stream>>>(H, ei, et, cnt, z2, E, N);
  }

  // --- decoder ---
  decoder_kernel<<<(P + 255) / 256, 256, 0, stream>>>(z2, pe, Wd1, bd1, Wd2, bd2, out, P);
}

// Round 2
// 852.471 us; speedup vs baseline: 2.8122x; 2.8122x over previous
//
#include <hip/hip_runtime.h>

// ---------------------------------------------------------------------------
// RGCN link predictor, fp32, CSR-pull aggregation (no float atomics).
//   rgcn_conv(x) = x@root + b + sum_r segsum_dst( H_r[src] ) / max(cnt_r[dst],1)
//   H_r = x @ W[r] per NODE (16x fewer FLOPs than per-edge).
//   Aggregation: build CSR by dst once (edges identical across layers), then
//   each node's wave pulls H[t][src][:] * inv[t][dst] over its edge list.
// ---------------------------------------------------------------------------

__global__ __launch_bounds__(256) void count_kernel(
    const int* __restrict__ ei, const int* __restrict__ et,
    float* __restrict__ cnt, int* __restrict__ deg, int E, int N) {
  int e = blockIdx.x * 256 + threadIdx.x;
  if (e >= E) return;
  int d = ei[E + e];
  int t = et[e];
  atomicAdd(&cnt[(size_t)t * N + d], 1.0f);
  atomicAdd(&deg[d], 1);
}

__global__ __launch_bounds__(256) void invert_kernel(float* __restrict__ cnt, int n) {
  int i = blockIdx.x * 256 + threadIdx.x;
  if (i < n) cnt[i] = 1.0f / fmaxf(cnt[i], 1.0f);
}

// ---- 2-level exclusive scan over deg[N] (N <= 512*256) ----
__global__ __launch_bounds__(256) void scan_block_kernel(
    const int* __restrict__ deg, int* __restrict__ excl, int* __restrict__ bsum, int n) {
  __shared__ int s[256];
  int tid = threadIdx.x;
  int i = blockIdx.x * 256 + tid;
  int v = (i < n) ? deg[i] : 0;
  s[tid] = v;
  __syncthreads();
  for (int off = 1; off < 256; off <<= 1) {
    int t = 0;
    if (tid >= off) t = s[tid - off];
    __syncthreads();
    s[tid] += t;
    __syncthreads();
  }
  if (i < n) excl[i] = s[tid] - v;
  if (tid == 255) bsum[blockIdx.x] = s[255];
}

__global__ __launch_bounds__(512) void scan_top_kernel(int* __restrict__ bsum, int nb) {
  __shared__ int s[512];
  int tid = threadIdx.x;
  int v = (tid < nb) ? bsum[tid] : 0;
  s[tid] = v;
  __syncthreads();
  for (int off = 1; off < 512; off <<= 1) {
    int t = 0;
    if (tid >= off) t = s[tid - off];
    __syncthreads();
    s[tid] += t;
    __syncthreads();
  }
  if (tid < nb) bsum[tid] = s[tid] - v;
}

__global__ __launch_bounds__(256) void add_offsets_kernel(
    int* __restrict__ startp, int* __restrict__ pos, const int* __restrict__ bsum, int n) {
  int i = blockIdx.x * 256 + threadIdx.x;
  if (i >= n) return;
  int v = startp[i] + bsum[blockIdx.x];
  startp[i] = v;
  pos[i] = v;
}

__global__ __launch_bounds__(256) void place_kernel(
    const int* __restrict__ ei, const int* __restrict__ et,
    int* __restrict__ pos, int* __restrict__ eSrcT, int E) {
  int e = blockIdx.x * 256 + threadIdx.x;
  if (e >= E) return;
  int s = ei[e];
  int d = ei[E + e];
  int t = et[e];
  int idx = atomicAdd(&pos[d], 1);
  eSrcT[idx] = s | (t << 20);  // src < 2^20, t < 4
}

// ---- pull aggregation: one wave per node ----
// C=64: lane = channel. z holds root part; fuse ReLU.
__global__ __launch_bounds__(256) void pull64_kernel(
    const float* __restrict__ H, const int* __restrict__ eSrcT,
    const int* __restrict__ startp, const int* __restrict__ deg,
    const float* __restrict__ inv, float* __restrict__ z, int N) {
  int w = (blockIdx.x * 256 + threadIdx.x) >> 6;
  int lane = threadIdx.x & 63;
  if (w >= N) return;
  int st = startp[w];
  int dg = deg[w];
  float sc0 = inv[w], sc1 = inv[N + w], sc2 = inv[2 * N + w];
  float v = z[(size_t)w * 64 + lane];
  for (int i = 0; i < dg; i++) {
    int p = eSrcT[st + i];
    int s = p & 0xFFFFF;
    int t = p >> 20;
    float sc = (t == 0) ? sc0 : ((t == 1) ? sc1 : sc2);
    v += H[((size_t)t * N + s) * 64 + lane] * sc;
  }
  z[(size_t)w * 64 + lane] = fmaxf(v, 0.0f);
}

// C=32: lanes 0-31 take even edges, 32-63 odd edges, xor-32 reduce at end.
__global__ __launch_bounds__(256) void pull32_kernel(
    const float* __restrict__ H, const int* __restrict__ eSrcT,
    const int* __restrict__ startp, const int* __restrict__ deg,
    const float* __restrict__ inv, float* __restrict__ z, int N) {
  int w = (blockIdx.x * 256 + threadIdx.x) >> 6;
  int lane = threadIdx.x & 63;
  int half = lane >> 5;
  int c = lane & 31;
  if (w >= N) return;
  int st = startp[w];
  int dg = deg[w];
  float sc0 = inv[w], sc1 = inv[N + w], sc2 = inv[2 * N + w];
  float v = 0.0f;
  for (int i = half; i < dg; i += 2) {
    int p = eSrcT[st + i];
    int s = p & 0xFFFFF;
    int t = p >> 20;
    float sc = (t == 0) ? sc0 : ((t == 1) ? sc1 : sc2);
    v += H[((size_t)t * N + s) * 32 + c] * sc;
  }
  v += __shfl_xor(v, 32);
  if (half == 0 && dg > 0) {
    size_t o = (size_t)w * 32 + c;
    z[o] += v;
  }
}

// Tiled GEMM: C[n x TN] = A[n x K] @ B[K x TN] (+bias). blockIdx.y selects
// which weight matrix (B += y*K*TN) and which output slab (C += y*n*TN).
template <int K, int TN>
__global__ __launch_bounds__(256) void gemm_kernel(
    const float* __restrict__ A, const float* __restrict__ B,
    const float* __restrict__ bias, float* __restrict__ C, int n) {
  __shared__ float As[64][K + 1];
  __shared__ float Bs[K][TN];
  const int tid = threadIdx.x;
  const int rowBase = blockIdx.x * 64;
  B += (size_t)blockIdx.y * K * TN;
  C += (size_t)blockIdx.y * (size_t)n * TN;

  for (int i = tid * 4; i < K * TN; i += 1024) {
    *(float4*)&Bs[0][i] = *(const float4*)&B[i];
  }
  for (int i = tid * 4; i < 64 * K; i += 1024) {
    int r = i / K, c = i % K;
    float4 v = make_float4(0.f, 0.f, 0.f, 0.f);
    if (rowBase + r < n) v = *(const float4*)&A[(size_t)(rowBase + r) * K + c];
    As[r][c] = v.x; As[r][c + 1] = v.y; As[r][c + 2] = v.z; As[r][c + 3] = v.w;
  }
  __syncthreads();

  constexpr int WN = TN / 16;
  const int row0 = (tid / 16) * 4;
  const int col0 = (tid % 16) * WN;

  float acc[4][WN];
#pragma unroll
  for (int i = 0; i < 4; i++)
#pragma unroll
    for (int j = 0; j < WN; j++) acc[i][j] = 0.0f;

#pragma unroll 8
  for (int k = 0; k < K; k++) {
    float a0 = As[row0][k], a1 = As[row0 + 1][k];
    float a2 = As[row0 + 2][k], a3 = As[row0 + 3][k];
#pragma unroll
    for (int j = 0; j < WN; j++) {
      float b = Bs[k][col0 + j];
      acc[0][j] += a0 * b;
      acc[1][j] += a1 * b;
      acc[2][j] += a2 * b;
      acc[3][j] += a3 * b;
    }
  }

#pragma unroll
  for (int i = 0; i < 4; i++) {
    int r = rowBase + row0 + i;
    if (r < n) {
#pragma unroll
      for (int j = 0; j < WN; j++) {
        float v = acc[i][j] + (bias ? bias[col0 + j] : 0.0f);
        C[(size_t)r * TN + col0 + j] = v;
      }
    }
  }
}

// Decoder: one thread per pred edge. Wd1 broadcast from LDS.
__global__ __launch_bounds__(256) void decoder_kernel(
    const float* __restrict__ z, const int* __restrict__ pe,
    const float* __restrict__ Wd1, const float* __restrict__ bd1,
    const float* __restrict__ Wd2, const float* __restrict__ bd2,
    float* __restrict__ out, int P) {
  __shared__ float W[64 * 64];
  __shared__ float w2[64], b1s[64];
  int tid = threadIdx.x;
  for (int i = tid * 4; i < 4096; i += 1024) *(float4*)&W[i] = *(const float4*)&Wd1[i];
  if (tid < 64) {
    w2[tid] = Wd2[tid];
    b1s[tid] = bd1[tid];
  }
  __syncthreads();
  int p = blockIdx.x * 256 + tid;
  if (p >= P) return;
  int s = pe[p];
  int d = pe[P + p];
  float zs[32], zd[32];
  const float4* ps4 = (const float4*)&z[(size_t)s * 32];
  const float4* pd4 = (const float4*)&z[(size_t)d * 32];
#pragma unroll
  for (int i = 0; i < 8; i++) {
    float4 a = ps4[i];
    zs[4 * i] = a.x; zs[4 * i + 1] = a.y; zs[4 * i + 2] = a.z; zs[4 * i + 3] = a.w;
    float4 b = pd4[i];
    zd[4 * i] = b.x; zd[4 * i + 1] = b.y; zd[4 * i + 2] = b.z; zd[4 * i + 3] = b.w;
  }
  float acc = bd2[0];
#pragma unroll 4
  for (int j = 0; j < 64; j++) {
    float h = b1s[j];
#pragma unroll
    for (int i = 0; i < 32; i++) h += zs[i] * W[i * 64 + j];
#pragma unroll
    for (int i = 0; i < 32; i++) h += zd[i] * W[(32 + i) * 64 + j];
    h = fmaxf(h, 0.0f);
    acc += h * w2[j];
  }
  out[p] = acc;
}

extern "C" void kernel_launch(void* const* d_in, const int* in_sizes, int n_in,
                              void* d_out, int out_size, void* d_ws, size_t ws_size,
                              hipStream_t stream) {
  const float* x     = (const float*)d_in[0];
  const int*   ei    = (const int*)d_in[1];
  const int*   et    = (const int*)d_in[2];
  const int*   pe    = (const int*)d_in[3];
  const float* W1    = (const float*)d_in[4];
  const float* root1 = (const float*)d_in[5];
  const float* b1    = (const float*)d_in[6];
  const float* W2    = (const float*)d_in[7];
  const float* root2 = (const float*)d_in[8];
  const float* b2    = (const float*)d_in[9];
  const float* Wd1   = (const float*)d_in[10];
  const float* bd1   = (const float*)d_in[11];
  const float* Wd2   = (const float*)d_in[12];
  const float* bd2   = (const float*)d_in[13];
  float* out = (float*)d_out;

  const int N = in_sizes[0] / 128;  // 100000
  const int E = in_sizes[2];        // 1600000
  const int P = in_sizes[3] / 2;    // 200000

  // Workspace layout:
  float* ws  = (float*)d_ws;
  float* cnt = ws;                          // 3N floats
  float* z1  = cnt + (size_t)3 * N;         // 64N
  float* z2  = z1 + (size_t)64 * N;         // 32N
  float* H   = z2 + (size_t)32 * N;         // 192N (3 * 64N, reused layer 2)
  int* deg    = (int*)(H + (size_t)192 * N);  // N
  int* startp = deg + N;                      // N
  int* pos    = startp + N;                   // N
  int* bsum   = pos + N;                      // 512
  int* eSrcT  = bsum + 512;                   // E

  const int nb = (N + 255) / 256;  // scan blocks (<= 512)

  // --- CSR build (edges shared by both layers) ---
  hipMemsetAsync(cnt, 0, (size_t)3 * N * sizeof(float), stream);
  hipMemsetAsync(deg, 0, (size_t)N * sizeof(int), stream);
  count_kernel<<<(E + 255) / 256, 256, 0, stream>>>(ei, et, cnt, deg, E, N);
  invert_kernel<<<(3 * N + 255) / 256, 256, 0, stream>>>(cnt, 3 * N);
  scan_block_kernel<<<nb, 256, 0, stream>>>(deg, startp, bsum, N);
  scan_top_kernel<<<1, 512, 0, stream>>>(bsum, nb);
  add_offsets_kernel<<<nb, 256, 0, stream>>>(startp, pos, bsum, N);
  place_kernel<<<(E + 255) / 256, 256, 0, stream>>>(ei, et, pos, eSrcT, E);

  const int gb = (N + 63) / 64;
  const int pullBlocks = (N * 64 + 255) / 256;

  // --- layer 1: K=128 -> 64 ---
  gemm_kernel<128, 64><<<dim3(gb, 3), 256, 0, stream>>>(x, W1, nullptr, H, N);
  gemm_kernel<128, 64><<<dim3(gb, 1), 256, 0, stream>>>(x, root1, b1, z1, N);
  pull64_kernel<<<pullBlocks, 256, 0, stream>>>(H, eSrcT, startp, deg, cnt, z1, N);

  // --- layer 2: K=64 -> 32 ---
  gemm_kernel<64, 32><<<dim3(gb, 3), 256, 0, stream>>>(z1, W2, nullptr, H, N);
  gemm_kernel<64, 32><<<dim3(gb, 1), 256, 0, stream>>>(z1, root2, b2, z2, N);
  pull32_kernel<<<pullBlocks, 256, 0, stream>>>(H, eSrcT, startp, deg, cnt, z2, N);

  // --- decoder ---
  decoder_kernel<<<(P + 255) / 256, 256, 0, stream>>>(z2, pe, Wd1, bd1, Wd2, bd2, out, P);
}

// Round 3
// 648.527 us; speedup vs baseline: 3.6966x; 1.3145x over previous
//
#include <hip/hip_runtime.h>

// ---------------------------------------------------------------------------
// RGCN link predictor, fp32, CSR-pull aggregation (no float atomics).
//   rgcn_conv(x) = x@root + b + sum_r segsum_dst( H_r[src] ) / max(cnt_r[dst],1)
//   H_r = x @ W[r] per NODE (16x fewer FLOPs than per-edge).
//   Pull kernels use float4 gathers: 16 (resp. 8) lanes per edge, 4 (resp. 8)
//   edges in flight per wave -> 4-8x memory-level parallelism vs scalar pull.
// ---------------------------------------------------------------------------

__global__ __launch_bounds__(256) void count_kernel(
    const int* __restrict__ ei, const int* __restrict__ et,
    int* __restrict__ cnt, int E, int N) {
  int e = blockIdx.x * 256 + threadIdx.x;
  if (e >= E) return;
  int d = ei[E + e];
  int t = et[e];
  atomicAdd(&cnt[(size_t)t * N + d], 1);
}

// inv[t][w] = 1/max(cnt,1); deg[w] = sum_t cnt[t][w]
__global__ __launch_bounds__(256) void prep_kernel(
    const int* __restrict__ cnt, float* __restrict__ inv,
    int* __restrict__ deg, int N) {
  int i = blockIdx.x * 256 + threadIdx.x;
  if (i >= N) return;
  int c0 = cnt[i], c1 = cnt[N + i], c2 = cnt[2 * N + i];
  inv[i]         = 1.0f / (float)max(c0, 1);
  inv[N + i]     = 1.0f / (float)max(c1, 1);
  inv[2 * N + i] = 1.0f / (float)max(c2, 1);
  deg[i] = c0 + c1 + c2;
}

// ---- 2-level exclusive scan over deg[N] (N <= 512*256) ----
__global__ __launch_bounds__(256) void scan_block_kernel(
    const int* __restrict__ deg, int* __restrict__ excl, int* __restrict__ bsum, int n) {
  __shared__ int s[256];
  int tid = threadIdx.x;
  int i = blockIdx.x * 256 + tid;
  int v = (i < n) ? deg[i] : 0;
  s[tid] = v;
  __syncthreads();
  for (int off = 1; off < 256; off <<= 1) {
    int t = 0;
    if (tid >= off) t = s[tid - off];
    __syncthreads();
    s[tid] += t;
    __syncthreads();
  }
  if (i < n) excl[i] = s[tid] - v;
  if (tid == 255) bsum[blockIdx.x] = s[255];
}

__global__ __launch_bounds__(512) void scan_top_kernel(int* __restrict__ bsum, int nb) {
  __shared__ int s[512];
  int tid = threadIdx.x;
  int v = (tid < nb) ? bsum[tid] : 0;
  s[tid] = v;
  __syncthreads();
  for (int off = 1; off < 512; off <<= 1) {
    int t = 0;
    if (tid >= off) t = s[tid - off];
    __syncthreads();
    s[tid] += t;
    __syncthreads();
  }
  if (tid < nb) bsum[tid] = s[tid] - v;
}

__global__ __launch_bounds__(256) void add_offsets_kernel(
    int* __restrict__ startp, int* __restrict__ pos, const int* __restrict__ bsum, int n) {
  int i = blockIdx.x * 256 + threadIdx.x;
  if (i >= n) return;
  int v = startp[i] + bsum[blockIdx.x];
  startp[i] = v;
  pos[i] = v;
}

__global__ __launch_bounds__(256) void place_kernel(
    const int* __restrict__ ei, const int* __restrict__ et,
    int* __restrict__ pos, int* __restrict__ eSrcT, int E) {
  int e = blockIdx.x * 256 + threadIdx.x;
  if (e >= E) return;
  int s = ei[e];
  int d = ei[E + e];
  int t = et[e];
  int idx = atomicAdd(&pos[d], 1);
  eSrcT[idx] = s | (t << 20);  // src < 2^20, t < 4
}

// ---- pull, C=64: one wave per node; 16 lanes x float4 per edge, 4 edges/iter.
__global__ __launch_bounds__(256) void pull64_kernel(
    const float4* __restrict__ H4, const int* __restrict__ eSrcT,
    const int* __restrict__ startp, const int* __restrict__ deg,
    const float* __restrict__ inv, float* __restrict__ z, int N) {
  int w = (blockIdx.x * 256 + threadIdx.x) >> 6;
  if (w >= N) return;
  int lane = threadIdx.x & 63;
  int g = lane >> 4;   // edge group 0..3
  int q = lane & 15;   // float4 index within 64-ch row
  int st = startp[w];
  int dg = deg[w];
  float sc0 = inv[w], sc1 = inv[N + w], sc2 = inv[2 * N + w];
  float4 acc = make_float4(0.f, 0.f, 0.f, 0.f);
  for (int i = g; i < dg; i += 4) {
    int p = eSrcT[st + i];
    int s = p & 0xFFFFF;
    int t = p >> 20;
    float sc = (t == 0) ? sc0 : ((t == 1) ? sc1 : sc2);
    float4 v = H4[((size_t)t * N + s) * 16 + q];
    acc.x += v.x * sc; acc.y += v.y * sc; acc.z += v.z * sc; acc.w += v.w * sc;
  }
  // reduce across the 4 edge groups (lanes q, q+16, q+32, q+48)
#pragma unroll
  for (int m = 16; m <= 32; m <<= 1) {
    acc.x += __shfl_xor(acc.x, m);
    acc.y += __shfl_xor(acc.y, m);
    acc.z += __shfl_xor(acc.z, m);
    acc.w += __shfl_xor(acc.w, m);
  }
  if (g == 0) {
    float4* zp = (float4*)z + (size_t)w * 16 + q;
    float4 zv = *zp;
    zv.x = fmaxf(zv.x + acc.x, 0.f);
    zv.y = fmaxf(zv.y + acc.y, 0.f);
    zv.z = fmaxf(zv.z + acc.z, 0.f);
    zv.w = fmaxf(zv.w + acc.w, 0.f);
    *zp = zv;
  }
}

// ---- pull, C=32: 8 lanes x float4 per edge, 8 edges/iter. No ReLU.
__global__ __launch_bounds__(256) void pull32_kernel(
    const float4* __restrict__ H4, const int* __restrict__ eSrcT,
    const int* __restrict__ startp, const int* __restrict__ deg,
    const float* __restrict__ inv, float* __restrict__ z, int N) {
  int w = (blockIdx.x * 256 + threadIdx.x) >> 6;
  if (w >= N) return;
  int lane = threadIdx.x & 63;
  int g = lane >> 3;  // edge group 0..7
  int q = lane & 7;   // float4 index within 32-ch row
  int st = startp[w];
  int dg = deg[w];
  float sc0 = inv[w], sc1 = inv[N + w], sc2 = inv[2 * N + w];
  float4 acc = make_float4(0.f, 0.f, 0.f, 0.f);
  for (int i = g; i < dg; i += 8) {
    int p = eSrcT[st + i];
    int s = p & 0xFFFFF;
    int t = p >> 20;
    float sc = (t == 0) ? sc0 : ((t == 1) ? sc1 : sc2);
    float4 v = H4[((size_t)t * N + s) * 8 + q];
    acc.x += v.x * sc; acc.y += v.y * sc; acc.z += v.z * sc; acc.w += v.w * sc;
  }
#pragma unroll
  for (int m = 8; m <= 32; m <<= 1) {
    acc.x += __shfl_xor(acc.x, m);
    acc.y += __shfl_xor(acc.y, m);
    acc.z += __shfl_xor(acc.z, m);
    acc.w += __shfl_xor(acc.w, m);
  }
  if (g == 0) {
    float4* zp = (float4*)z + (size_t)w * 8 + q;
    float4 zv = *zp;
    zv.x += acc.x; zv.y += acc.y; zv.z += acc.z; zv.w += acc.w;
    *zp = zv;
  }
}

// Tiled GEMM over 4 weight slabs: y<3 -> H[y] = A @ W[y];  y==3 -> z = A @ root + b.
template <int K, int TN>
__global__ __launch_bounds__(256) void gemm_all_kernel(
    const float* __restrict__ A, const float* __restrict__ W,
    const float* __restrict__ root, const float* __restrict__ bias,
    float* __restrict__ H, float* __restrict__ z, int n) {
  __shared__ float As[64][K + 1];
  __shared__ float Bs[K][TN];
  const int tid = threadIdx.x;
  const int rowBase = blockIdx.x * 64;
  const int y = blockIdx.y;
  const float* B;
  const float* bi;
  float* C;
  if (y < 3) {
    B = W + (size_t)y * K * TN;
    C = H + (size_t)y * (size_t)n * TN;
    bi = nullptr;
  } else {
    B = root;
    C = z;
    bi = bias;
  }

  for (int i = tid * 4; i < K * TN; i += 1024) {
    *(float4*)&Bs[0][i] = *(const float4*)&B[i];
  }
  for (int i = tid * 4; i < 64 * K; i += 1024) {
    int r = i / K, c = i % K;
    float4 v = make_float4(0.f, 0.f, 0.f, 0.f);
    if (rowBase + r < n) v = *(const float4*)&A[(size_t)(rowBase + r) * K + c];
    As[r][c] = v.x; As[r][c + 1] = v.y; As[r][c + 2] = v.z; As[r][c + 3] = v.w;
  }
  __syncthreads();

  constexpr int WN = TN / 16;
  const int row0 = (tid / 16) * 4;
  const int col0 = (tid % 16) * WN;

  float acc[4][WN];
#pragma unroll
  for (int i = 0; i < 4; i++)
#pragma unroll
    for (int j = 0; j < WN; j++) acc[i][j] = 0.0f;

#pragma unroll 8
  for (int k = 0; k < K; k++) {
    float a0 = As[row0][k], a1 = As[row0 + 1][k];
    float a2 = As[row0 + 2][k], a3 = As[row0 + 3][k];
#pragma unroll
    for (int j = 0; j < WN; j++) {
      float b = Bs[k][col0 + j];
      acc[0][j] += a0 * b;
      acc[1][j] += a1 * b;
      acc[2][j] += a2 * b;
      acc[3][j] += a3 * b;
    }
  }

#pragma unroll
  for (int i = 0; i < 4; i++) {
    int r = rowBase + row0 + i;
    if (r < n) {
#pragma unroll
      for (int j = 0; j < WN; j++) {
        float v = acc[i][j] + (bi ? bi[col0 + j] : 0.0f);
        C[(size_t)r * TN + col0 + j] = v;
      }
    }
  }
}

// Decoder: one thread per pred edge. Wd1 broadcast from LDS.
__global__ __launch_bounds__(256) void decoder_kernel(
    const float* __restrict__ z, const int* __restrict__ pe,
    const float* __restrict__ Wd1, const float* __restrict__ bd1,
    const float* __restrict__ Wd2, const float* __restrict__ bd2,
    float* __restrict__ out, int P) {
  __shared__ float W[64 * 64];
  __shared__ float w2[64], b1s[64];
  int tid = threadIdx.x;
  for (int i = tid * 4; i < 4096; i += 1024) *(float4*)&W[i] = *(const float4*)&Wd1[i];
  if (tid < 64) {
    w2[tid] = Wd2[tid];
    b1s[tid] = bd1[tid];
  }
  __syncthreads();
  int p = blockIdx.x * 256 + tid;
  if (p >= P) return;
  int s = pe[p];
  int d = pe[P + p];
  float zs[32], zd[32];
  const float4* ps4 = (const float4*)&z[(size_t)s * 32];
  const float4* pd4 = (const float4*)&z[(size_t)d * 32];
#pragma unroll
  for (int i = 0; i < 8; i++) {
    float4 a = ps4[i];
    zs[4 * i] = a.x; zs[4 * i + 1] = a.y; zs[4 * i + 2] = a.z; zs[4 * i + 3] = a.w;
    float4 b = pd4[i];
    zd[4 * i] = b.x; zd[4 * i + 1] = b.y; zd[4 * i + 2] = b.z; zd[4 * i + 3] = b.w;
  }
  float acc = bd2[0];
#pragma unroll 4
  for (int j = 0; j < 64; j++) {
    float h = b1s[j];
#pragma unroll
    for (int i = 0; i < 32; i++) h += zs[i] * W[i * 64 + j];
#pragma unroll
    for (int i = 0; i < 32; i++) h += zd[i] * W[(32 + i) * 64 + j];
    h = fmaxf(h, 0.0f);
    acc += h * w2[j];
  }
  out[p] = acc;
}

extern "C" void kernel_launch(void* const* d_in, const int* in_sizes, int n_in,
                              void* d_out, int out_size, void* d_ws, size_t ws_size,
                              hipStream_t stream) {
  const float* x     = (const float*)d_in[0];
  const int*   ei    = (const int*)d_in[1];
  const int*   et    = (const int*)d_in[2];
  const int*   pe    = (const int*)d_in[3];
  const float* W1    = (const float*)d_in[4];
  const float* root1 = (const float*)d_in[5];
  const float* b1    = (const float*)d_in[6];
  const float* W2    = (const float*)d_in[7];
  const float* root2 = (const float*)d_in[8];
  const float* b2    = (const float*)d_in[9];
  const float* Wd1   = (const float*)d_in[10];
  const float* bd1   = (const float*)d_in[11];
  const float* Wd2   = (const float*)d_in[12];
  const float* bd2   = (const float*)d_in[13];
  float* out = (float*)d_out;

  const int N = in_sizes[0] / 128;  // 100000
  const int E = in_sizes[2];        // 1600000
  const int P = in_sizes[3] / 2;    // 200000

  // Workspace layout (all 16B-aligned; N is even so 4*k*N is 16B-multiple
  // whenever k is even; offsets below use even multipliers of N).
  float* ws   = (float*)d_ws;
  float* inv  = ws;                            // 3N+pad -> use 4N slot
  float* z1   = ws + (size_t)4 * N;            // 64N
  float* z2   = z1 + (size_t)64 * N;           // 32N
  float* H    = z2 + (size_t)32 * N;           // 192N (3 x 64N, reused layer 2)
  int* cnt    = (int*)(H + (size_t)192 * N);   // 3N (int)
  int* deg    = cnt + (size_t)3 * N;           // N
  int* startp = deg + N;                       // N
  int* pos    = startp + N;                    // N
  int* bsum   = pos + N;                       // 512
  int* eSrcT  = bsum + 512;                    // E

  const int nb = (N + 255) / 256;  // scan blocks (<= 512)

  // --- CSR build (edges shared by both layers) ---
  hipMemsetAsync(cnt, 0, (size_t)3 * N * sizeof(int), stream);
  count_kernel<<<(E + 255) / 256, 256, 0, stream>>>(ei, et, cnt, E, N);
  prep_kernel<<<nb, 256, 0, stream>>>(cnt, inv, deg, N);
  scan_block_kernel<<<nb, 256, 0, stream>>>(deg, startp, bsum, N);
  scan_top_kernel<<<1, 512, 0, stream>>>(bsum, nb);
  add_offsets_kernel<<<nb, 256, 0, stream>>>(startp, pos, bsum, N);
  place_kernel<<<(E + 255) / 256, 256, 0, stream>>>(ei, et, pos, eSrcT, E);

  const int gb = (N + 63) / 64;
  const int pullBlocks = (N * 64 + 255) / 256;

  // --- layer 1: K=128 -> 64 (3 relation slabs + root in one grid) ---
  gemm_all_kernel<128, 64><<<dim3(gb, 4), 256, 0, stream>>>(x, W1, root1, b1, H, z1, N);
  pull64_kernel<<<pullBlocks, 256, 0, stream>>>((const float4*)H, eSrcT, startp, deg, inv, z1, N);

  // --- layer 2: K=64 -> 32 ---
  gemm_all_kernel<64, 32><<<dim3(gb, 4), 256, 0, stream>>>(z1, W2, root2, b2, H, z2, N);
  pull32_kernel<<<pullBlocks, 256, 0, stream>>>((const float4*)H, eSrcT, startp, deg, inv, z2, N);

  // --- decoder ---
  decoder_kernel<<<(P + 255) / 256, 256, 0, stream>>>(z2, pe, Wd1, bd1, Wd2, bd2, out, P);
}

// Round 4
// 573.637 us; speedup vs baseline: 4.1792x; 1.1306x over previous
//
#include <hip/hip_runtime.h>

// ---------------------------------------------------------------------------
// RGCN link predictor. CSR-pull aggregation + split-precision bf16 MFMA GEMMs.
//   rgcn_conv(x) = x@root + b + sum_r segsum_dst( H_r[src] ) / max(cnt_r[dst],1)
//   GEMM emulates fp32 via bf16 split: A*B = Ah*Bh + Al*Bh + Ah*Bl  (3 passes,
//   missing Al*Bl ~ 2^-18 relative). A staged to LDS in MFMA fragment order;
//   B pre-packed to fragment order in global (tiny, L1-resident).
// ---------------------------------------------------------------------------

typedef short bf16x8 __attribute__((ext_vector_type(8)));
typedef float f32x4 __attribute__((ext_vector_type(4)));

__device__ __forceinline__ unsigned short f2bf(float f) {
  union { float f; unsigned u; } x; x.f = f;
  unsigned r = x.u + 0x7FFF + ((x.u >> 16) & 1);  // RNE
  return (unsigned short)(r >> 16);
}
__device__ __forceinline__ float bf2f(unsigned short h) {
  union { unsigned u; float f; } x; x.u = ((unsigned)h) << 16;
  return x.f;
}

__global__ __launch_bounds__(256) void count_kernel(
    const int* __restrict__ ei, const int* __restrict__ et,
    int* __restrict__ cnt, int E, int N) {
  int e = blockIdx.x * 256 + threadIdx.x;
  if (e >= E) return;
  int d = ei[E + e];
  int t = et[e];
  atomicAdd(&cnt[(size_t)t * N + d], 1);
}

__global__ __launch_bounds__(256) void prep_kernel(
    const int* __restrict__ cnt, float* __restrict__ inv,
    int* __restrict__ deg, int N) {
  int i = blockIdx.x * 256 + threadIdx.x;
  if (i >= N) return;
  int c0 = cnt[i], c1 = cnt[N + i], c2 = cnt[2 * N + i];
  inv[i]         = 1.0f / (float)max(c0, 1);
  inv[N + i]     = 1.0f / (float)max(c1, 1);
  inv[2 * N + i] = 1.0f / (float)max(c2, 1);
  deg[i] = c0 + c1 + c2;
}

__global__ __launch_bounds__(256) void scan_block_kernel(
    const int* __restrict__ deg, int* __restrict__ excl, int* __restrict__ bsum, int n) {
  __shared__ int s[256];
  int tid = threadIdx.x;
  int i = blockIdx.x * 256 + tid;
  int v = (i < n) ? deg[i] : 0;
  s[tid] = v;
  __syncthreads();
  for (int off = 1; off < 256; off <<= 1) {
    int t = 0;
    if (tid >= off) t = s[tid - off];
    __syncthreads();
    s[tid] += t;
    __syncthreads();
  }
  if (i < n) excl[i] = s[tid] - v;
  if (tid == 255) bsum[blockIdx.x] = s[255];
}

__global__ __launch_bounds__(512) void scan_top_kernel(int* __restrict__ bsum, int nb) {
  __shared__ int s[512];
  int tid = threadIdx.x;
  int v = (tid < nb) ? bsum[tid] : 0;
  s[tid] = v;
  __syncthreads();
  for (int off = 1; off < 512; off <<= 1) {
    int t = 0;
    if (tid >= off) t = s[tid - off];
    __syncthreads();
    s[tid] += t;
    __syncthreads();
  }
  if (tid < nb) bsum[tid] = s[tid] - v;
}

__global__ __launch_bounds__(256) void add_offsets_kernel(
    int* __restrict__ startp, int* __restrict__ pos, const int* __restrict__ bsum, int n) {
  int i = blockIdx.x * 256 + threadIdx.x;
  if (i >= n) return;
  int v = startp[i] + bsum[blockIdx.x];
  startp[i] = v;
  pos[i] = v;
}

__global__ __launch_bounds__(256) void place_kernel(
    const int* __restrict__ ei, const int* __restrict__ et,
    int* __restrict__ pos, int* __restrict__ eSrcT, int E) {
  int e = blockIdx.x * 256 + threadIdx.x;
  if (e >= E) return;
  int s = ei[e];
  int d = ei[E + e];
  int t = et[e];
  int idx = atomicAdd(&pos[d], 1);
  eSrcT[idx] = s | (t << 20);  // src < 2^20, t < 4
}

// split fp32 -> (hi, lo) bf16, 4 elems/thread
__global__ __launch_bounds__(256) void split_kernel(
    const float4* __restrict__ in, ushort4* __restrict__ hi,
    ushort4* __restrict__ lo, int n4) {
  int i = blockIdx.x * 256 + threadIdx.x;
  if (i >= n4) return;
  float4 v = in[i];
  ushort4 h, l;
  h.x = f2bf(v.x); l.x = f2bf(v.x - bf2f(h.x));
  h.y = f2bf(v.y); l.y = f2bf(v.y - bf2f(h.y));
  h.z = f2bf(v.z); l.z = f2bf(v.z - bf2f(h.z));
  h.w = f2bf(v.w); l.w = f2bf(v.w - bf2f(h.w));
  hi[i] = h; lo[i] = l;
}

// pack weights (3 relation slabs + root) into MFMA B-fragment order, split hi/lo.
__global__ __launch_bounds__(256) void packw_kernel(
    const float* __restrict__ W, const float* __restrict__ root,
    ushort* __restrict__ Bh, ushort* __restrict__ Bl, int K, int TN) {
  int e = blockIdx.x * 256 + threadIdx.x;
  if (e >= 4 * K * TN) return;
  int slab = e / (K * TN), r = e % (K * TN);
  int k = r / TN, n = r % TN;
  float v = (slab < 3) ? W[(size_t)slab * K * TN + k * TN + n] : root[(size_t)k * TN + n];
  int kc = k >> 5, quad = (k >> 3) & 3, j = k & 7, nt = n >> 4, nn = n & 15;
  int NTt = TN / 16;
  int didx = slab * K * TN + ((kc * NTt + nt) * 64 + quad * 16 + nn) * 8 + j;
  unsigned short h = f2bf(v);
  Bh[didx] = h;
  Bl[didx] = f2bf(v - bf2f(h));
}

// Split-bf16 MFMA GEMM. Block = 128 rows x TN cols, 4 waves (wave = 32 rows).
// slabs 0..2 -> H[slab] = A@W[slab]; slab 3 -> z = A@root + bias.
// acc = Ah*Bh + Al*Bh + Ah*Bl over 3 passes, fp32 accumulate.
template <int K, int TN>
__global__ __launch_bounds__(256) void mfma_gemm_kernel(
    const ushort* __restrict__ Ahi, const ushort* __restrict__ Alo,
    const ushort* __restrict__ Bh, const ushort* __restrict__ Bl,
    const float* __restrict__ bias, float* __restrict__ H,
    float* __restrict__ z, int n) {
  constexpr int KC = K / 32;        // 32-k chunks
  constexpr int NTt = TN / 16;      // col tiles
  constexpr int KB = K / 8;         // 8-elem groups along K
  constexpr int CPA = 128 * K / 8;  // 16B chunks per A array
  __shared__ int4 ls[2][CPA];
  const int tid = threadIdx.x;
  const int rowBase = blockIdx.x * 128;

  // stage A (hi+lo) into LDS in fragment order: chunk (kc, mt) holds lanes'
  // 16B frags contiguously -> frag read = ds_read_b128 at base + lane*16.
  for (int c = tid; c < CPA; c += 256) {
    int r = c / KB, kq = c % KB;
    int lch = ((kq >> 2) * 8 + (r >> 4)) * 64 + (kq & 3) * 16 + (r & 15);
    int g = rowBase + r;
    int4 vh = make_int4(0, 0, 0, 0), vl = vh;
    if (g < n) {
      vh = *(const int4*)&Ahi[(size_t)g * K + kq * 8];
      vl = *(const int4*)&Alo[(size_t)g * K + kq * 8];
    }
    ls[0][lch] = vh;
    ls[1][lch] = vl;
  }
  __syncthreads();

  const int w = tid >> 6, lane = tid & 63;
  const int quad = lane >> 4, nn = lane & 15;
  const short* lsp0 = (const short*)&ls[0][0];
  const short* lsp1 = (const short*)&ls[1][0];

#pragma unroll 1
  for (int slab = 0; slab < 4; slab++) {
    f32x4 acc[2][NTt];
#pragma unroll
    for (int i = 0; i < 2; i++)
#pragma unroll
      for (int j = 0; j < NTt; j++) acc[i][j] = (f32x4){0.f, 0.f, 0.f, 0.f};

#pragma unroll 1
    for (int pass = 0; pass < 3; pass++) {
      const short* As = (pass == 1) ? lsp1 : lsp0;
      const ushort* Bs = ((pass == 2) ? Bl : Bh) + (size_t)slab * K * TN;
#pragma unroll
      for (int kc = 0; kc < KC; kc++) {
        bf16x8 a0 = *(const bf16x8*)&As[(((kc * 8 + w * 2 + 0) * 64) + lane) * 8];
        bf16x8 a1 = *(const bf16x8*)&As[(((kc * 8 + w * 2 + 1) * 64) + lane) * 8];
#pragma unroll
        for (int nt = 0; nt < NTt; nt++) {
          bf16x8 b = *(const bf16x8*)&Bs[((kc * NTt + nt) * 64 + lane) * 8];
          acc[0][nt] = __builtin_amdgcn_mfma_f32_16x16x32_bf16(a0, b, acc[0][nt], 0, 0, 0);
          acc[1][nt] = __builtin_amdgcn_mfma_f32_16x16x32_bf16(a1, b, acc[1][nt], 0, 0, 0);
        }
      }
    }

    // epilogue: D row = quad*4+reg, col = lane&15 (m89-verified)
#pragma unroll
    for (int mt = 0; mt < 2; mt++) {
      int grow0 = rowBase + w * 32 + mt * 16 + quad * 4;
#pragma unroll
      for (int nt = 0; nt < NTt; nt++) {
        int col = nt * 16 + nn;
#pragma unroll
        for (int rg = 0; rg < 4; rg++) {
          int grow = grow0 + rg;
          if (grow < n) {
            float v = acc[mt][nt][rg];
            if (slab == 3) z[(size_t)grow * TN + col] = v + bias[col];
            else H[((size_t)slab * n + grow) * TN + col] = v;
          }
        }
      }
    }
  }
}

// ---- pull, C=64: one wave per node; 16 lanes x float4 per edge, 4 edges/iter.
__global__ __launch_bounds__(256) void pull64_kernel(
    const float4* __restrict__ H4, const int* __restrict__ eSrcT,
    const int* __restrict__ startp, const int* __restrict__ deg,
    const float* __restrict__ inv, float* __restrict__ z, int N) {
  int w = (blockIdx.x * 256 + threadIdx.x) >> 6;
  if (w >= N) return;
  int lane = threadIdx.x & 63;
  int g = lane >> 4;
  int q = lane & 15;
  int st = startp[w];
  int dg = deg[w];
  float sc0 = inv[w], sc1 = inv[N + w], sc2 = inv[2 * N + w];
  float4 acc = make_float4(0.f, 0.f, 0.f, 0.f);
  for (int i = g; i < dg; i += 4) {
    int p = eSrcT[st + i];
    int s = p & 0xFFFFF;
    int t = p >> 20;
    float sc = (t == 0) ? sc0 : ((t == 1) ? sc1 : sc2);
    float4 v = H4[((size_t)t * N + s) * 16 + q];
    acc.x += v.x * sc; acc.y += v.y * sc; acc.z += v.z * sc; acc.w += v.w * sc;
  }
#pragma unroll
  for (int m = 16; m <= 32; m <<= 1) {
    acc.x += __shfl_xor(acc.x, m);
    acc.y += __shfl_xor(acc.y, m);
    acc.z += __shfl_xor(acc.z, m);
    acc.w += __shfl_xor(acc.w, m);
  }
  if (g == 0) {
    float4* zp = (float4*)z + (size_t)w * 16 + q;
    float4 zv = *zp;
    zv.x = fmaxf(zv.x + acc.x, 0.f);
    zv.y = fmaxf(zv.y + acc.y, 0.f);
    zv.z = fmaxf(zv.z + acc.z, 0.f);
    zv.w = fmaxf(zv.w + acc.w, 0.f);
    *zp = zv;
  }
}

// ---- pull, C=32: 8 lanes x float4 per edge, 8 edges/iter. No ReLU.
__global__ __launch_bounds__(256) void pull32_kernel(
    const float4* __restrict__ H4, const int* __restrict__ eSrcT,
    const int* __restrict__ startp, const int* __restrict__ deg,
    const float* __restrict__ inv, float* __restrict__ z, int N) {
  int w = (blockIdx.x * 256 + threadIdx.x) >> 6;
  if (w >= N) return;
  int lane = threadIdx.x & 63;
  int g = lane >> 3;
  int q = lane & 7;
  int st = startp[w];
  int dg = deg[w];
  float sc0 = inv[w], sc1 = inv[N + w], sc2 = inv[2 * N + w];
  float4 acc = make_float4(0.f, 0.f, 0.f, 0.f);
  for (int i = g; i < dg; i += 8) {
    int p = eSrcT[st + i];
    int s = p & 0xFFFFF;
    int t = p >> 20;
    float sc = (t == 0) ? sc0 : ((t == 1) ? sc1 : sc2);
    float4 v = H4[((size_t)t * N + s) * 8 + q];
    acc.x += v.x * sc; acc.y += v.y * sc; acc.z += v.z * sc; acc.w += v.w * sc;
  }
#pragma unroll
  for (int m = 8; m <= 32; m <<= 1) {
    acc.x += __shfl_xor(acc.x, m);
    acc.y += __shfl_xor(acc.y, m);
    acc.z += __shfl_xor(acc.z, m);
    acc.w += __shfl_xor(acc.w, m);
  }
  if (g == 0) {
    float4* zp = (float4*)z + (size_t)w * 8 + q;
    float4 zv = *zp;
    zv.x += acc.x; zv.y += acc.y; zv.z += acc.z; zv.w += acc.w;
    *zp = zv;
  }
}

// Decoder: one thread per pred edge. Wd1 broadcast from LDS.
__global__ __launch_bounds__(256) void decoder_kernel(
    const float* __restrict__ z, const int* __restrict__ pe,
    const float* __restrict__ Wd1, const float* __restrict__ bd1,
    const float* __restrict__ Wd2, const float* __restrict__ bd2,
    float* __restrict__ out, int P) {
  __shared__ float W[64 * 64];
  __shared__ float w2[64], b1s[64];
  int tid = threadIdx.x;
  for (int i = tid * 4; i < 4096; i += 1024) *(float4*)&W[i] = *(const float4*)&Wd1[i];
  if (tid < 64) {
    w2[tid] = Wd2[tid];
    b1s[tid] = bd1[tid];
  }
  __syncthreads();
  int p = blockIdx.x * 256 + tid;
  if (p >= P) return;
  int s = pe[p];
  int d = pe[P + p];
  float zs[32], zd[32];
  const float4* ps4 = (const float4*)&z[(size_t)s * 32];
  const float4* pd4 = (const float4*)&z[(size_t)d * 32];
#pragma unroll
  for (int i = 0; i < 8; i++) {
    float4 a = ps4[i];
    zs[4 * i] = a.x; zs[4 * i + 1] = a.y; zs[4 * i + 2] = a.z; zs[4 * i + 3] = a.w;
    float4 b = pd4[i];
    zd[4 * i] = b.x; zd[4 * i + 1] = b.y; zd[4 * i + 2] = b.z; zd[4 * i + 3] = b.w;
  }
  float acc = bd2[0];
#pragma unroll 4
  for (int j = 0; j < 64; j++) {
    float h = b1s[j];
#pragma unroll
    for (int i = 0; i < 32; i++) h += zs[i] * W[i * 64 + j];
#pragma unroll
    for (int i = 0; i < 32; i++) h += zd[i] * W[(32 + i) * 64 + j];
    h = fmaxf(h, 0.0f);
    acc += h * w2[j];
  }
  out[p] = acc;
}

extern "C" void kernel_launch(void* const* d_in, const int* in_sizes, int n_in,
                              void* d_out, int out_size, void* d_ws, size_t ws_size,
                              hipStream_t stream) {
  const float* x     = (const float*)d_in[0];
  const int*   ei    = (const int*)d_in[1];
  const int*   et    = (const int*)d_in[2];
  const int*   pe    = (const int*)d_in[3];
  const float* W1    = (const float*)d_in[4];
  const float* root1 = (const float*)d_in[5];
  const float* b1    = (const float*)d_in[6];
  const float* W2    = (const float*)d_in[7];
  const float* root2 = (const float*)d_in[8];
  const float* b2    = (const float*)d_in[9];
  const float* Wd1   = (const float*)d_in[10];
  const float* bd1   = (const float*)d_in[11];
  const float* Wd2   = (const float*)d_in[12];
  const float* bd2   = (const float*)d_in[13];
  float* out = (float*)d_out;

  const int N = in_sizes[0] / 128;  // 100000
  const int E = in_sizes[2];        // 1600000
  const int P = in_sizes[3] / 2;    // 200000

  // Workspace layout (float units; N % 4 == 0 so k*N offsets are 16B-aligned):
  //   inv:0..4N  z1:4N..68N  z2:68N..100N  H:100N..292N
  //   splits:292N..420N  (xh 128N ushorts @292N, xl @356N; z1h/z1l overlay)
  //   Bpack:420N..421N  ints:421N..
  float* ws  = (float*)d_ws;
  float* inv = ws;
  float* z1  = ws + (size_t)4 * N;
  float* z2  = ws + (size_t)68 * N;
  float* H   = ws + (size_t)100 * N;
  ushort* xh  = (ushort*)(ws + (size_t)292 * N);  // N*128 bf16
  ushort* xl  = (ushort*)(ws + (size_t)356 * N);
  ushort* z1h = (ushort*)(ws + (size_t)292 * N);  // overlay: x splits dead by then
  ushort* z1l = (ushort*)(ws + (size_t)324 * N);
  ushort* Bh1 = (ushort*)(ws + (size_t)420 * N);  // 4*128*64
  ushort* Bl1 = Bh1 + 32768;
  ushort* Bh2 = Bl1 + 32768;                      // 4*64*32
  ushort* Bl2 = Bh2 + 8192;
  int* ibase  = (int*)(ws + (size_t)421 * N);
  int* cnt    = ibase;                 // 3N
  int* deg    = ibase + (size_t)3 * N; // N
  int* startp = ibase + (size_t)4 * N; // N
  int* pos    = ibase + (size_t)5 * N; // N
  int* bsum   = ibase + (size_t)6 * N; // 512
  int* eSrcT  = bsum + 512;            // E

  const int nb = (N + 255) / 256;

  // --- CSR build (edges shared by both layers) ---
  hipMemsetAsync(cnt, 0, (size_t)3 * N * sizeof(int), stream);
  count_kernel<<<(E + 255) / 256, 256, 0, stream>>>(ei, et, cnt, E, N);
  prep_kernel<<<nb, 256, 0, stream>>>(cnt, inv, deg, N);
  scan_block_kernel<<<nb, 256, 0, stream>>>(deg, startp, bsum, N);
  scan_top_kernel<<<1, 512, 0, stream>>>(bsum, nb);
  add_offsets_kernel<<<nb, 256, 0, stream>>>(startp, pos, bsum, N);
  place_kernel<<<(E + 255) / 256, 256, 0, stream>>>(ei, et, pos, eSrcT, E);

  // --- splits & weight packing ---
  split_kernel<<<(N * 128 / 4 + 255) / 256, 256, 0, stream>>>(
      (const float4*)x, (ushort4*)xh, (ushort4*)xl, N * 128 / 4);
  packw_kernel<<<(4 * 128 * 64 + 255) / 256, 256, 0, stream>>>(W1, root1, Bh1, Bl1, 128, 64);
  packw_kernel<<<(4 * 64 * 32 + 255) / 256, 256, 0, stream>>>(W2, root2, Bh2, Bl2, 64, 32);

  const int gb = (N + 127) / 128;
  const int pullBlocks = (N * 64 + 255) / 256;

  // --- layer 1: K=128 -> 64 ---
  mfma_gemm_kernel<128, 64><<<gb, 256, 0, stream>>>(xh, xl, Bh1, Bl1, b1, H, z1, N);
  pull64_kernel<<<pullBlocks, 256, 0, stream>>>((const float4*)H, eSrcT, startp, deg, inv, z1, N);

  // --- layer 2: K=64 -> 32 ---
  split_kernel<<<(N * 64 / 4 + 255) / 256, 256, 0, stream>>>(
      (const float4*)z1, (ushort4*)z1h, (ushort4*)z1l, N * 64 / 4);
  mfma_gemm_kernel<64, 32><<<gb, 256, 0, stream>>>(z1h, z1l, Bh2, Bl2, b2, H, z2, N);
  pull32_kernel<<<pullBlocks, 256, 0, stream>>>((const float4*)H, eSrcT, startp, deg, inv, z2, N);

  // --- decoder ---
  decoder_kernel<<<(P + 255) / 256, 256, 0, stream>>>(z2, pe, Wd1, bd1, Wd2, bd2, out, P);
}

// Round 5
// 454.906 us; speedup vs baseline: 5.2700x; 1.2610x over previous
//
#include <hip/hip_runtime.h>

// ---------------------------------------------------------------------------
// RGCN link predictor. Atomic-free CSR build + CSR-pull + split-bf16 MFMA GEMM.
//   rgcn_conv(x) = x@root + b + sum_r segsum_dst( H_r[src] ) / max(cnt_r[dst],1)
//   CSR build: MSD 2-level bucket sort by dst (within-dst order is irrelevant),
//   all returning atomics are LDS-local (global atomics write through 64B/op).
//   GEMM: fp32 via bf16 split (Ah*Bh + Al*Bh + Ah*Bl), split fused into LDS
//   staging. B pre-packed to fragment order in global (tiny, L1-resident).
// ---------------------------------------------------------------------------

typedef short bf16x8 __attribute__((ext_vector_type(8)));
typedef float f32x4 __attribute__((ext_vector_type(4)));

__device__ __forceinline__ unsigned short f2bf(float f) {
  union { float f; unsigned u; } x; x.f = f;
  unsigned r = x.u + 0x7FFF + ((x.u >> 16) & 1);  // RNE
  return (unsigned short)(r >> 16);
}
__device__ __forceinline__ float bf2f(unsigned short h) {
  union { unsigned u; float f; } x; x.u = ((unsigned)h) << 16;
  return x.f;
}

// ---- level-1 partition: histogram of dst>>9 per block tile ----
__global__ __launch_bounds__(256) void part_hist_kernel(
    const int* __restrict__ ei, int* __restrict__ hist,
    int E, int tile, int NBUCK) {
  __shared__ int lh[256];
  int tid = threadIdx.x;
  lh[tid] = 0;
  __syncthreads();
  int e0 = blockIdx.x * tile;
  int e1 = min(E, e0 + tile);
  for (int e = e0 + tid; e < e1; e += 256) {
    int d = ei[E + e];
    atomicAdd(&lh[d >> 9], 1);
  }
  __syncthreads();
  if (tid < NBUCK) hist[tid * 256 + blockIdx.x] = lh[tid];
}

// scan hist rows (bucket-major) + bucket bases; rewrite hist to global cursors
__global__ __launch_bounds__(256) void part_scan_kernel(
    int* __restrict__ hist, int* __restrict__ bstart, int NBUCK) {
  __shared__ int sA[256], sB[256];
  int t = threadIdx.x;
  int tot = 0;
  if (t < NBUCK) {
    int* row = hist + t * 256;
    for (int i = 0; i < 256; i++) { int v = row[i]; row[i] = tot; tot += v; }
  }
  sA[t] = tot;
  __syncthreads();
  int* src = sA; int* dst = sB;
  for (int off = 1; off < 256; off <<= 1) {
    int v = src[t];
    if (t >= off) v += src[t - off];
    dst[t] = v;
    __syncthreads();
    int* tmp = src; src = dst; dst = tmp;
  }
  int base = src[t] - tot;  // exclusive
  if (t < NBUCK) {
    bstart[t] = base;
    int* row = hist + t * 256;
    for (int i = 0; i < 256; i++) row[i] += base;
    if (t == NBUCK - 1) bstart[NBUCK] = base + tot;
  }
}

// scatter edges into coarse buckets (LDS cursors, plain global stores)
__global__ __launch_bounds__(256) void part_scatter_kernel(
    const int* __restrict__ ei, const int* __restrict__ et,
    const int* __restrict__ hist, uint2* __restrict__ rec,
    int E, int tile, int NBUCK) {
  __shared__ int ctr[256];
  int tid = threadIdx.x;
  ctr[tid] = (tid < NBUCK) ? hist[tid * 256 + blockIdx.x] : 0;
  __syncthreads();
  int e0 = blockIdx.x * tile;
  int e1 = min(E, e0 + tile);
  for (int e = e0 + tid; e < e1; e += 256) {
    int s = ei[e];
    int d = ei[E + e];
    int t = et[e];
    int p = atomicAdd(&ctr[d >> 9], 1);
    rec[p] = make_uint2((unsigned)(s | (t << 20)), (unsigned)d);
  }
}

// ---- level-2: one block per bucket (dst window of 512). Produces per-(rel,dst)
// inv, deg, startp and the final dst-grouped eSrcT — LDS atomics only.
__global__ __launch_bounds__(256) void bucket_build_kernel(
    const uint2* __restrict__ rec, const int* __restrict__ bstart,
    float* __restrict__ inv, int* __restrict__ deg, int* __restrict__ startp,
    int* __restrict__ eSrcT, int N) {
  __shared__ int c3[1536];
  __shared__ int sA[512], sB[512];
  __shared__ int cur[512];
  int tid = threadIdx.x;
  int dstBase = blockIdx.x << 9;
  int bs = bstart[blockIdx.x], be = bstart[blockIdx.x + 1];
  for (int i = tid; i < 1536; i += 256) c3[i] = 0;
  __syncthreads();
  for (int i = bs + tid; i < be; i += 256) {
    uint2 r = rec[i];
    atomicAdd(&c3[(r.x >> 20) * 512 + (r.y & 511)], 1);
  }
  __syncthreads();
  for (int i = tid; i < 512; i += 256) {
    int d = dstBase + i;
    int c0 = c3[i], c1 = c3[512 + i], c2 = c3[1024 + i];
    int dg = c0 + c1 + c2;
    sA[i] = dg;
    if (d < N) {
      deg[d] = dg;
      inv[d]         = 1.0f / (float)max(c0, 1);
      inv[N + d]     = 1.0f / (float)max(c1, 1);
      inv[2 * N + d] = 1.0f / (float)max(c2, 1);
    }
  }
  __syncthreads();
  int* src = sA; int* dst = sB;
  for (int off = 1; off < 512; off <<= 1) {
    for (int i = tid; i < 512; i += 256) {
      int v = src[i];
      if (i >= off) v += src[i - off];
      dst[i] = v;
    }
    __syncthreads();
    int* tmp = src; src = dst; dst = tmp;
  }
  for (int i = tid; i < 512; i += 256) {
    int excl = (i > 0) ? src[i - 1] : 0;
    cur[i] = bs + excl;
    int d = dstBase + i;
    if (d < N) startp[d] = bs + excl;
  }
  __syncthreads();
  for (int i = bs + tid; i < be; i += 256) {
    uint2 r = rec[i];
    int p = atomicAdd(&cur[r.y & 511], 1);
    eSrcT[p] = (int)r.x;
  }
}

// pack weights (3 relation slabs + root) into MFMA B-fragment order, split hi/lo.
__global__ __launch_bounds__(256) void packw_kernel(
    const float* __restrict__ W, const float* __restrict__ root,
    ushort* __restrict__ Bh, ushort* __restrict__ Bl, int K, int TN) {
  int e = blockIdx.x * 256 + threadIdx.x;
  if (e >= 4 * K * TN) return;
  int slab = e / (K * TN), r = e % (K * TN);
  int k = r / TN, n = r % TN;
  float v = (slab < 3) ? W[(size_t)slab * K * TN + k * TN + n] : root[(size_t)k * TN + n];
  int kc = k >> 5, quad = (k >> 3) & 3, j = k & 7, nt = n >> 4, nn = n & 15;
  int NTt = TN / 16;
  int didx = slab * K * TN + ((kc * NTt + nt) * 64 + quad * 16 + nn) * 8 + j;
  unsigned short h = f2bf(v);
  Bh[didx] = h;
  Bl[didx] = f2bf(v - bf2f(h));
}

// Split-bf16 MFMA GEMM. Block = 128 rows x TN cols, 4 waves (wave = 32 rows).
// A is fp32; hi/lo split happens in-register during LDS staging.
// slabs 0..2 -> H[slab] = A@W[slab]; slab 3 -> z = A@root + bias.
template <int K, int TN>
__global__ __launch_bounds__(256) void mfma_gemm_kernel(
    const float* __restrict__ A, const ushort* __restrict__ Bh,
    const ushort* __restrict__ Bl, const float* __restrict__ bias,
    float* __restrict__ H, float* __restrict__ z, int n) {
  constexpr int KC = K / 32;        // 32-k chunks
  constexpr int NTt = TN / 16;      // col tiles
  constexpr int KB = K / 8;         // 8-elem groups along K
  constexpr int CPA = 128 * K / 8;  // 16B chunks per A array
  __shared__ int4 ls[2][CPA];
  const int tid = threadIdx.x;
  const int rowBase = blockIdx.x * 128;

  for (int c = tid; c < CPA; c += 256) {
    int r = c / KB, kq = c % KB;
    int lch = ((kq >> 2) * 8 + (r >> 4)) * 64 + (kq & 3) * 16 + (r & 15);
    int g = rowBase + r;
    int4 vh = make_int4(0, 0, 0, 0), vl = vh;
    if (g < n) {
      const float* ap = &A[(size_t)g * K + kq * 8];
      float4 f0 = *(const float4*)ap;
      float4 f1 = *(const float4*)(ap + 4);
      float f[8] = {f0.x, f0.y, f0.z, f0.w, f1.x, f1.y, f1.z, f1.w};
      unsigned short h[8], l[8];
#pragma unroll
      for (int j = 0; j < 8; j++) {
        h[j] = f2bf(f[j]);
        l[j] = f2bf(f[j] - bf2f(h[j]));
      }
      vh = make_int4((int)(h[0] | (h[1] << 16)), (int)(h[2] | (h[3] << 16)),
                     (int)(h[4] | (h[5] << 16)), (int)(h[6] | (h[7] << 16)));
      vl = make_int4((int)(l[0] | (l[1] << 16)), (int)(l[2] | (l[3] << 16)),
                     (int)(l[4] | (l[5] << 16)), (int)(l[6] | (l[7] << 16)));
    }
    ls[0][lch] = vh;
    ls[1][lch] = vl;
  }
  __syncthreads();

  const int w = tid >> 6, lane = tid & 63;
  const int quad = lane >> 4, nn = lane & 15;
  const short* lsp0 = (const short*)&ls[0][0];
  const short* lsp1 = (const short*)&ls[1][0];

#pragma unroll 1
  for (int slab = 0; slab < 4; slab++) {
    f32x4 acc[2][NTt];
#pragma unroll
    for (int i = 0; i < 2; i++)
#pragma unroll
      for (int j = 0; j < NTt; j++) acc[i][j] = (f32x4){0.f, 0.f, 0.f, 0.f};

#pragma unroll 1
    for (int pass = 0; pass < 3; pass++) {
      const short* As = (pass == 1) ? lsp1 : lsp0;
      const ushort* Bs = ((pass == 2) ? Bl : Bh) + (size_t)slab * K * TN;
#pragma unroll
      for (int kc = 0; kc < KC; kc++) {
        bf16x8 a0 = *(const bf16x8*)&As[(((kc * 8 + w * 2 + 0) * 64) + lane) * 8];
        bf16x8 a1 = *(const bf16x8*)&As[(((kc * 8 + w * 2 + 1) * 64) + lane) * 8];
#pragma unroll
        for (int nt = 0; nt < NTt; nt++) {
          bf16x8 b = *(const bf16x8*)&Bs[((kc * NTt + nt) * 64 + lane) * 8];
          acc[0][nt] = __builtin_amdgcn_mfma_f32_16x16x32_bf16(a0, b, acc[0][nt], 0, 0, 0);
          acc[1][nt] = __builtin_amdgcn_mfma_f32_16x16x32_bf16(a1, b, acc[1][nt], 0, 0, 0);
        }
      }
    }

    // epilogue: D row = quad*4+reg, col = lane&15 (m89-verified)
#pragma unroll
    for (int mt = 0; mt < 2; mt++) {
      int grow0 = rowBase + w * 32 + mt * 16 + quad * 4;
#pragma unroll
      for (int nt = 0; nt < NTt; nt++) {
        int col = nt * 16 + nn;
#pragma unroll
        for (int rg = 0; rg < 4; rg++) {
          int grow = grow0 + rg;
          if (grow < n) {
            float v = acc[mt][nt][rg];
            if (slab == 3) z[(size_t)grow * TN + col] = v + bias[col];
            else H[((size_t)slab * n + grow) * TN + col] = v;
          }
        }
      }
    }
  }
}

// ---- pull, C=64: one wave per node; 16 lanes x float4 per edge, 4 edges/iter.
__global__ __launch_bounds__(256) void pull64_kernel(
    const float4* __restrict__ H4, const int* __restrict__ eSrcT,
    const int* __restrict__ startp, const int* __restrict__ deg,
    const float* __restrict__ inv, float* __restrict__ z, int N) {
  int w = (blockIdx.x * 256 + threadIdx.x) >> 6;
  if (w >= N) return;
  int lane = threadIdx.x & 63;
  int g = lane >> 4;
  int q = lane & 15;
  int st = startp[w];
  int dg = deg[w];
  float sc0 = inv[w], sc1 = inv[N + w], sc2 = inv[2 * N + w];
  float4 acc = make_float4(0.f, 0.f, 0.f, 0.f);
  for (int i = g; i < dg; i += 4) {
    int p = eSrcT[st + i];
    int s = p & 0xFFFFF;
    int t = p >> 20;
    float sc = (t == 0) ? sc0 : ((t == 1) ? sc1 : sc2);
    float4 v = H4[((size_t)t * N + s) * 16 + q];
    acc.x += v.x * sc; acc.y += v.y * sc; acc.z += v.z * sc; acc.w += v.w * sc;
  }
#pragma unroll
  for (int m = 16; m <= 32; m <<= 1) {
    acc.x += __shfl_xor(acc.x, m);
    acc.y += __shfl_xor(acc.y, m);
    acc.z += __shfl_xor(acc.z, m);
    acc.w += __shfl_xor(acc.w, m);
  }
  if (g == 0) {
    float4* zp = (float4*)z + (size_t)w * 16 + q;
    float4 zv = *zp;
    zv.x = fmaxf(zv.x + acc.x, 0.f);
    zv.y = fmaxf(zv.y + acc.y, 0.f);
    zv.z = fmaxf(zv.z + acc.z, 0.f);
    zv.w = fmaxf(zv.w + acc.w, 0.f);
    *zp = zv;
  }
}

// ---- pull, C=32: 8 lanes x float4 per edge, 8 edges/iter. No ReLU.
__global__ __launch_bounds__(256) void pull32_kernel(
    const float4* __restrict__ H4, const int* __restrict__ eSrcT,
    const int* __restrict__ startp, const int* __restrict__ deg,
    const float* __restrict__ inv, float* __restrict__ z, int N) {
  int w = (blockIdx.x * 256 + threadIdx.x) >> 6;
  if (w >= N) return;
  int lane = threadIdx.x & 63;
  int g = lane >> 3;
  int q = lane & 7;
  int st = startp[w];
  int dg = deg[w];
  float sc0 = inv[w], sc1 = inv[N + w], sc2 = inv[2 * N + w];
  float4 acc = make_float4(0.f, 0.f, 0.f, 0.f);
  for (int i = g; i < dg; i += 8) {
    int p = eSrcT[st + i];
    int s = p & 0xFFFFF;
    int t = p >> 20;
    float sc = (t == 0) ? sc0 : ((t == 1) ? sc1 : sc2);
    float4 v = H4[((size_t)t * N + s) * 8 + q];
    acc.x += v.x * sc; acc.y += v.y * sc; acc.z += v.z * sc; acc.w += v.w * sc;
  }
#pragma unroll
  for (int m = 8; m <= 32; m <<= 1) {
    acc.x += __shfl_xor(acc.x, m);
    acc.y += __shfl_xor(acc.y, m);
    acc.z += __shfl_xor(acc.z, m);
    acc.w += __shfl_xor(acc.w, m);
  }
  if (g == 0) {
    float4* zp = (float4*)z + (size_t)w * 8 + q;
    float4 zv = *zp;
    zv.x += acc.x; zv.y += acc.y; zv.z += acc.z; zv.w += acc.w;
    *zp = zv;
  }
}

// Decoder: one thread per pred edge. Wd1 broadcast from LDS.
__global__ __launch_bounds__(256) void decoder_kernel(
    const float* __restrict__ z, const int* __restrict__ pe,
    const float* __restrict__ Wd1, const float* __restrict__ bd1,
    const float* __restrict__ Wd2, const float* __restrict__ bd2,
    float* __restrict__ out, int P) {
  __shared__ float W[64 * 64];
  __shared__ float w2[64], b1s[64];
  int tid = threadIdx.x;
  for (int i = tid * 4; i < 4096; i += 1024) *(float4*)&W[i] = *(const float4*)&Wd1[i];
  if (tid < 64) {
    w2[tid] = Wd2[tid];
    b1s[tid] = bd1[tid];
  }
  __syncthreads();
  int p = blockIdx.x * 256 + tid;
  if (p >= P) return;
  int s = pe[p];
  int d = pe[P + p];
  float zs[32], zd[32];
  const float4* ps4 = (const float4*)&z[(size_t)s * 32];
  const float4* pd4 = (const float4*)&z[(size_t)d * 32];
#pragma unroll
  for (int i = 0; i < 8; i++) {
    float4 a = ps4[i];
    zs[4 * i] = a.x; zs[4 * i + 1] = a.y; zs[4 * i + 2] = a.z; zs[4 * i + 3] = a.w;
    float4 b = pd4[i];
    zd[4 * i] = b.x; zd[4 * i + 1] = b.y; zd[4 * i + 2] = b.z; zd[4 * i + 3] = b.w;
  }
  float acc = bd2[0];
#pragma unroll 4
  for (int j = 0; j < 64; j++) {
    float h = b1s[j];
#pragma unroll
    for (int i = 0; i < 32; i++) h += zs[i] * W[i * 64 + j];
#pragma unroll
    for (int i = 0; i < 32; i++) h += zd[i] * W[(32 + i) * 64 + j];
    h = fmaxf(h, 0.0f);
    acc += h * w2[j];
  }
  out[p] = acc;
}

extern "C" void kernel_launch(void* const* d_in, const int* in_sizes, int n_in,
                              void* d_out, int out_size, void* d_ws, size_t ws_size,
                              hipStream_t stream) {
  const float* x     = (const float*)d_in[0];
  const int*   ei    = (const int*)d_in[1];
  const int*   et    = (const int*)d_in[2];
  const int*   pe    = (const int*)d_in[3];
  const float* W1    = (const float*)d_in[4];
  const float* root1 = (const float*)d_in[5];
  const float* b1    = (const float*)d_in[6];
  const float* W2    = (const float*)d_in[7];
  const float* root2 = (const float*)d_in[8];
  const float* b2    = (const float*)d_in[9];
  const float* Wd1   = (const float*)d_in[10];
  const float* bd1   = (const float*)d_in[11];
  const float* Wd2   = (const float*)d_in[12];
  const float* bd2   = (const float*)d_in[13];
  float* out = (float*)d_out;

  const int N = in_sizes[0] / 128;  // 100000
  const int E = in_sizes[2];        // 1600000
  const int P = in_sizes[3] / 2;    // 200000

  const int NBUCK = (N + 511) >> 9;         // coarse buckets (dst>>9), <=256
  const int tile  = (E + 255) / 256;        // edges per partition block

  // Workspace layout (float units; all offsets 16B-aligned for even N):
  //   inv:0..4N  z1:4N..68N  z2:68N..100N  H:100N..292N  Bpack:292N..293N
  //   ints from 293N: deg N | startp N | bstart 1K | hist NBUCK*256 | rec 2E | eSrcT E
  float* ws  = (float*)d_ws;
  float* inv = ws;
  float* z1  = ws + (size_t)4 * N;
  float* z2  = ws + (size_t)68 * N;
  float* H   = ws + (size_t)100 * N;
  ushort* Bh1 = (ushort*)(ws + (size_t)292 * N);  // 4*128*64
  ushort* Bl1 = Bh1 + 32768;
  ushort* Bh2 = Bl1 + 32768;                      // 4*64*32
  ushort* Bl2 = Bh2 + 8192;
  int* ib     = (int*)(ws + (size_t)293 * N);
  int* deg    = ib;
  int* startp = ib + N;
  int* bstart = ib + 2 * (size_t)N;               // NBUCK+1 (pad to 1024)
  int* hist   = ib + 2 * (size_t)N + 1024;        // NBUCK*256
  size_t roff = 2 * (size_t)N + 1024 + (size_t)NBUCK * 256;
  roff = (roff + 3) & ~(size_t)3;                 // 16B align for uint2
  uint2* rec  = (uint2*)(ib + roff);              // E records
  int* eSrcT  = ib + roff + 2 * (size_t)E;        // E

  // --- CSR build: 2-level bucket sort, LDS atomics only ---
  part_hist_kernel<<<256, 256, 0, stream>>>(ei, hist, E, tile, NBUCK);
  part_scan_kernel<<<1, 256, 0, stream>>>(hist, bstart, NBUCK);
  part_scatter_kernel<<<256, 256, 0, stream>>>(ei, et, hist, rec, E, tile, NBUCK);
  bucket_build_kernel<<<NBUCK, 256, 0, stream>>>(rec, bstart, inv, deg, startp, eSrcT, N);

  // --- weight packing (tiny) ---
  packw_kernel<<<(4 * 128 * 64 + 255) / 256, 256, 0, stream>>>(W1, root1, Bh1, Bl1, 128, 64);
  packw_kernel<<<(4 * 64 * 32 + 255) / 256, 256, 0, stream>>>(W2, root2, Bh2, Bl2, 64, 32);

  const int gb = (N + 127) / 128;
  const int pullBlocks = (N * 64 + 255) / 256;

  // --- layer 1: K=128 -> 64 ---
  mfma_gemm_kernel<128, 64><<<gb, 256, 0, stream>>>(x, Bh1, Bl1, b1, H, z1, N);
  pull64_kernel<<<pullBlocks, 256, 0, stream>>>((const float4*)H, eSrcT, startp, deg, inv, z1, N);

  // --- layer 2: K=64 -> 32 (split fused into staging; reads z1 fp32) ---
  mfma_gemm_kernel<64, 32><<<gb, 256, 0, stream>>>(z1, Bh2, Bl2, b2, H, z2, N);
  pull32_kernel<<<pullBlocks, 256, 0, stream>>>((const float4*)H, eSrcT, startp, deg, inv, z2, N);

  // --- decoder ---
  decoder_kernel<<<(P + 255) / 256, 256, 0, stream>>>(z2, pe, Wd1, bd1, Wd2, bd2, out, P);
}